// Round 5
// baseline (133.237 us; speedup 1.0000x reference)
//
#include <hip/hip_runtime.h>

// Problem constants (fixed by the reference)
#define TT    8192          // tokens
#define TOPK  8
#define HH    2048          // hidden
#define EE    64            // experts
#define NFLAT (TT * TOPK)   // 65536 flat (token, slot) pairs
#define NBLK  (NFLAT / 256) // 256 chunks of 256 slots
#define NSEG  16            // scan segments (NBLK / 16 chunks each)

typedef float f32x4 __attribute__((ext_vector_type(4)));

// ---------------------------------------------------------------------------
// Kernel 1: per-chunk expert histogram + stable in-chunk rank per slot.
// rank[i] = number of j < i within the chunk with the same expert.
// ---------------------------------------------------------------------------
__global__ void k_hist_rank(const int* __restrict__ expi,
                            int* __restrict__ blockHist,
                            int* __restrict__ rank) {
    __shared__ int sh_e[256];
    __shared__ int sh_hist[EE];
    const int tid = threadIdx.x;
    const int gid = blockIdx.x * 256 + tid;
    if (tid < EE) sh_hist[tid] = 0;
    const int e = expi[gid];
    sh_e[tid] = e;
    __syncthreads();
    atomicAdd(&sh_hist[e], 1);          // LDS histogram (order-independent)
    int r = 0;
    for (int j = 0; j < tid; ++j) r += (sh_e[j] == e) ? 1 : 0;
    rank[gid] = r;
    __syncthreads();
    if (tid < EE) blockHist[blockIdx.x * EE + tid] = sh_hist[tid];
}

// ---------------------------------------------------------------------------
// Kernel 2: parallel scan. One block, 1024 threads = 16 segments x 64 experts.
// chunkBase[b][e] = (# slots with expert < e) + (# slots expert e, chunk < b).
// Also emits splits (as float; d_out is f32).
// ---------------------------------------------------------------------------
__global__ void k_scan(const int* __restrict__ bh,
                       int* __restrict__ cb,
                       float* __restrict__ splits_out) {
    __shared__ int part[NSEG][EE];
    __shared__ int segbase[NSEG][EE];
    __shared__ int ebase[EE + 1];
    const int t = threadIdx.x;
    const int s = t >> 6;        // segment 0..15
    const int e = t & 63;        // expert
    int sum = 0;
#pragma unroll
    for (int b = 0; b < NBLK / NSEG; ++b)
        sum += bh[(s * (NBLK / NSEG) + b) * EE + e];
    part[s][e] = sum;
    __syncthreads();
    if (s == 0) {                // 64 threads: scan 16 segments per expert
        int acc = 0;
#pragma unroll
        for (int i = 0; i < NSEG; ++i) { segbase[i][e] = acc; acc += part[i][e]; }
        splits_out[e] = (float)acc;   // per-expert total
        ebase[e + 1] = acc;
    }
    __syncthreads();
    if (t == 0) {
        ebase[0] = 0;
        for (int i = 1; i <= EE; ++i) ebase[i] += ebase[i - 1];
    }
    __syncthreads();
    int run = ebase[e] + segbase[s][e];
#pragma unroll
    for (int b = 0; b < NBLK / NSEG; ++b) {
        const int idx = (s * (NBLK / NSEG) + b) * EE + e;
        cb[idx] = run;
        run += bh[idx];
    }
}

// ---------------------------------------------------------------------------
// Kernel 3: half-row dispatch + fused combine. 2 blocks per token, 4 KB each.
// Routing indices and weight-sum are block-uniform -> scalar loads, no LDS,
// no barrier. Each thread: 1 f32x4 load, 9 nontemporal f32x4 stores.
// ---------------------------------------------------------------------------
__global__ __launch_bounds__(256)
void k_dispatch_tok(const float* __restrict__ x,
                    const float* __restrict__ w,
                    const int* __restrict__ expi,
                    const int* __restrict__ chunkBase,
                    const int* __restrict__ rank,
                    float* __restrict__ disp,
                    float* __restrict__ comb) {
    const int bid  = blockIdx.x;
    const int tok  = bid >> 1;                 // token
    const int half = bid & 1;                  // which 4 KB half of the row
    const int tid  = threadIdx.x;
    const int off  = half * 256 + tid;         // f32x4 index within the row

    // Block-uniform routing: 8 dest rows (scalar s_load chains)
    int dbase[TOPK];
#pragma unroll
    for (int k = 0; k < TOPK; ++k) {
        const int i = tok * TOPK + k;
        const int e = expi[i];
        dbase[k] = chunkBase[(i >> 8) * EE + e] + rank[i];
    }
    float sw = 0.f;                            // block-uniform weight sum
#pragma unroll
    for (int k = 0; k < TOPK; ++k) sw += w[tok * TOPK + k];

    const f32x4 a = ((const f32x4*)(x + (size_t)tok * HH))[off];

    f32x4* __restrict__ cd = (f32x4*)(comb + (size_t)tok * HH);
    __builtin_nontemporal_store(a * sw, &cd[off]);
#pragma unroll
    for (int s = 0; s < TOPK; ++s) {
        f32x4* __restrict__ dst = (f32x4*)(disp + (size_t)dbase[s] * HH);
        __builtin_nontemporal_store(a, &dst[off]);
    }
}

extern "C" void kernel_launch(void* const* d_in, const int* in_sizes, int n_in,
                              void* d_out, int out_size, void* d_ws, size_t ws_size,
                              hipStream_t stream) {
    const float* x    = (const float*)d_in[0];   // [T, H]
    const float* w    = (const float*)d_in[1];   // [T, TOPK]
    const int*   expi = (const int*)d_in[2];     // [T, TOPK]

    float* out    = (float*)d_out;
    float* disp   = out;                                  // [T*K, H]
    float* splits = out + (size_t)NFLAT * HH;             // [E]
    float* comb   = splits + EE;                          // [T, H]

    int* ws        = (int*)d_ws;
    int* blockHist = ws;                 // [NBLK][E]
    int* chunkBase = ws + NBLK * EE;     // [NBLK][E]
    int* rank      = ws + 2 * NBLK * EE; // [NFLAT]

    k_hist_rank<<<NBLK, 256, 0, stream>>>(expi, blockHist, rank);
    k_scan<<<1, 1024, 0, stream>>>(blockHist, chunkBase, splits);
    k_dispatch_tok<<<2 * TT, 256, 0, stream>>>(x, w, expi, chunkBase, rank, disp, comb);
}

// Round 6
// 126.882 us; speedup vs baseline: 1.0501x; 1.0501x over previous
//
#include <hip/hip_runtime.h>

// Problem constants (fixed by the reference)
#define TT    8192          // tokens
#define TOPK  8
#define HH    2048          // hidden
#define EE    64            // experts
#define NFLAT (TT * TOPK)   // 65536 flat (token, slot) pairs
#define NBLK  (NFLAT / 256) // 256 chunks of 256 slots
#define NSEG  16            // scan segments (NBLK / 16 chunks each)

typedef float f32x4 __attribute__((ext_vector_type(4)));

// ---------------------------------------------------------------------------
// Kernel 1: per-chunk expert histogram + stable in-chunk rank per slot.
// rank[i] = number of j < i within the chunk with the same expert.
// ---------------------------------------------------------------------------
__global__ void k_hist_rank(const int* __restrict__ expi,
                            int* __restrict__ blockHist,
                            int* __restrict__ rank) {
    __shared__ int sh_e[256];
    __shared__ int sh_hist[EE];
    const int tid = threadIdx.x;
    const int gid = blockIdx.x * 256 + tid;
    if (tid < EE) sh_hist[tid] = 0;
    const int e = expi[gid];
    sh_e[tid] = e;
    __syncthreads();
    atomicAdd(&sh_hist[e], 1);          // LDS histogram (order-independent)
    int r = 0;
    for (int j = 0; j < tid; ++j) r += (sh_e[j] == e) ? 1 : 0;
    rank[gid] = r;
    __syncthreads();
    if (tid < EE) blockHist[blockIdx.x * EE + tid] = sh_hist[tid];
}

// ---------------------------------------------------------------------------
// Kernel 2: parallel scan. One block, 1024 threads = 16 segments x 64 experts.
// chunkBase[b][e] = (# slots with expert < e) + (# slots expert e, chunk < b).
// Also emits splits (as float; d_out is f32).
// ---------------------------------------------------------------------------
__global__ void k_scan(const int* __restrict__ bh,
                       int* __restrict__ cb,
                       float* __restrict__ splits_out) {
    __shared__ int part[NSEG][EE];
    __shared__ int segbase[NSEG][EE];
    __shared__ int ebase[EE + 1];
    const int t = threadIdx.x;
    const int s = t >> 6;        // segment 0..15
    const int e = t & 63;        // expert
    int sum = 0;
#pragma unroll
    for (int b = 0; b < NBLK / NSEG; ++b)
        sum += bh[(s * (NBLK / NSEG) + b) * EE + e];
    part[s][e] = sum;
    __syncthreads();
    if (s == 0) {                // 64 threads: scan 16 segments per expert
        int acc = 0;
#pragma unroll
        for (int i = 0; i < NSEG; ++i) { segbase[i][e] = acc; acc += part[i][e]; }
        splits_out[e] = (float)acc;   // per-expert total
        ebase[e + 1] = acc;
    }
    __syncthreads();
    if (t == 0) {
        ebase[0] = 0;
        for (int i = 1; i <= EE; ++i) ebase[i] += ebase[i - 1];
    }
    __syncthreads();
    int run = ebase[e] + segbase[s][e];
#pragma unroll
    for (int b = 0; b < NBLK / NSEG; ++b) {
        const int idx = (s * (NBLK / NSEG) + b) * EE + e;
        cb[idx] = run;
        run += bh[idx];
    }
}

// ---------------------------------------------------------------------------
// Kernel 3: token-major dispatch + fused combine. ONE block per token,
// 512 threads: each thread owns one f32x4 (16 B) of the 8 KB row.
// 1 load + 9 nontemporal stores per thread. Metadata (8 dest indices,
// weight-sum) is block-uniform -> scalar loads, no LDS, no barrier.
// Read traffic = 64 MB compulsory; writes = 576 MB write-once streams.
// ---------------------------------------------------------------------------
__global__ __launch_bounds__(512)
void k_dispatch_tok(const float* __restrict__ x,
                    const float* __restrict__ w,
                    const int* __restrict__ expi,
                    const int* __restrict__ chunkBase,
                    const int* __restrict__ rank,
                    float* __restrict__ disp,
                    float* __restrict__ comb) {
    const int tok = blockIdx.x;
    const int off = threadIdx.x;               // f32x4 index within the row

    // Block-uniform routing: 8 dest rows (scalar s_load chains)
    int dbase[TOPK];
#pragma unroll
    for (int k = 0; k < TOPK; ++k) {
        const int i = tok * TOPK + k;
        const int e = expi[i];
        dbase[k] = chunkBase[(i >> 8) * EE + e] + rank[i];
    }
    float sw = 0.f;                            // block-uniform weight sum
#pragma unroll
    for (int k = 0; k < TOPK; ++k) sw += w[tok * TOPK + k];

    const f32x4 a = ((const f32x4*)(x + (size_t)tok * HH))[off];

    f32x4* __restrict__ cd = (f32x4*)(comb + (size_t)tok * HH);
    __builtin_nontemporal_store(a * sw, &cd[off]);
#pragma unroll
    for (int s = 0; s < TOPK; ++s) {
        f32x4* __restrict__ dst = (f32x4*)(disp + (size_t)dbase[s] * HH);
        __builtin_nontemporal_store(a, &dst[off]);
    }
}

extern "C" void kernel_launch(void* const* d_in, const int* in_sizes, int n_in,
                              void* d_out, int out_size, void* d_ws, size_t ws_size,
                              hipStream_t stream) {
    const float* x    = (const float*)d_in[0];   // [T, H]
    const float* w    = (const float*)d_in[1];   // [T, TOPK]
    const int*   expi = (const int*)d_in[2];     // [T, TOPK]

    float* out    = (float*)d_out;
    float* disp   = out;                                  // [T*K, H]
    float* splits = out + (size_t)NFLAT * HH;             // [E]
    float* comb   = splits + EE;                          // [T, H]

    int* ws        = (int*)d_ws;
    int* blockHist = ws;                 // [NBLK][E]
    int* chunkBase = ws + NBLK * EE;     // [NBLK][E]
    int* rank      = ws + 2 * NBLK * EE; // [NFLAT]

    k_hist_rank<<<NBLK, 256, 0, stream>>>(expi, blockHist, rank);
    k_scan<<<1, 1024, 0, stream>>>(blockHist, chunkBase, splits);
    k_dispatch_tok<<<TT, 512, 0, stream>>>(x, w, expi, chunkBase, rank, disp, comb);
}